// Round 2
// baseline (147.355 us; speedup 1.0000x reference)
//
#include <hip/hip_runtime.h>

// binary_decoder: bit-exact float32 emulation of the reference's sequential
// carry-save adder.
//
// Round-6 changes (diagnosis: csa_main at 42.7us = ~50 cy/step vs ~20 cy
// issue and ~24 cy dependence cycle -> single-chain waves leave ~26 cy/step
// of dependence stall the compiler will not fill across step boundaries;
// scheduling hints only got 61->50):
//  - TWO independent chains per wave (og and og+32, same b). The two
//    chains' instruction streams interleave in-order, so each chain's
//    dependence gaps are filled by the other chain's issue. Shared per
//    step: x readlane + nothing else; per-chain: sbfe, and, dpp, 2 add,
//    cmp, 2 cndmask -> ~17 VALU / f-step for BOTH chains (~34 cy issue).
//  - Grid 8x4x8 = 256 one-wave blocks = exactly 1 per CU.
//  - Per-chain op sequence unchanged (bit-exact, absmax 0.0 rounds 1-5):
//    a = sext(bit) & x; uu = s+a; t = uu+dpp(h_prev); ge = t>=2;
//    h = ge?kmask:0; s = ge?t-2:t.   Final c = dpp(h_last).
//
// Fixed harness floor (not controllable): 256 MB workspace re-poison
// (fillBufferAligned, ~43us) is inside the timed region.

#define F_DIM 2048
#define K_DIM 4096
#define B_DIM 8
#define G     32            // steps per group = bits per packed dword
#define NG    (F_DIM / G)   // 64 groups
#define NSB   (F_DIM / 64)  // 32 superblocks of 64 steps

#define PK_BYTES (64 * NG * 64 * 4)  // 1 MB: [og][f32][lane] dwords

__device__ __forceinline__ float dpp_row_shr1(float v) {
    // row_shr:1 (0x111), all rows/banks, bound_ctrl: out-of-row source -> 0
    int r = __builtin_amdgcn_update_dpp(0, __float_as_int(v), 0x111, 0xf, 0xf, true);
    return __int_as_float(r);
}

__device__ __forceinline__ int sext_bit(unsigned bits, int u) {
#if __has_builtin(__builtin_amdgcn_sbfe)
    return __builtin_amdgcn_sbfe((int)bits, (unsigned)u, 1u);  // v_bfe_i32
#else
    return ((int)(bits << (31 - u))) >> 31;
#endif
}

// ---------------- pass 1: pack (w >= 0.5) bits -----------------------------
// pk[(og*64 + f32)*64 + lane] bit j = (w[(f32*32+j)][og*64+lane] >= 0.5)
__global__ __launch_bounds__(64) void pack_kernel(const float* __restrict__ w,
                                                  unsigned* __restrict__ pk) {
    const int lane = threadIdx.x;      // 0..63 -> column within og
    const int og   = blockIdx.x;       // 0..63
    const int f32  = blockIdx.y;       // 0..63
    const float* wp = w + og * 64 + lane;
    unsigned bits = 0;
#pragma unroll
    for (int j = 0; j < 32; ++j) {
        float wv = wp[(f32 * 32 + j) * K_DIM];   // coalesced 256B per j
        bits |= (wv >= 0.5f ? 1u : 0u) << j;
    }
    pk[(og * 64 + f32) * 64 + lane] = bits;
}

// ---------------- pass 2: the sequential chains (2 per wave) ---------------
__global__ __launch_bounds__(64, 1) void csa_main(const float* __restrict__ x,
                                                  const unsigned* __restrict__ pk,
                                                  float* __restrict__ out) {
    const int lane = threadIdx.x;                 // 0..63
    const int ogp  = blockIdx.x + 8 * blockIdx.y; // 0..31
    const int b    = blockIdx.z;                  // 0..7
    const int og0  = ogp;
    const int og1  = ogp + 32;
    const int k0   = og0 * 64 + lane;
    const int k1   = og1 * 64 + lane;

    // 1.0 everywhere except the MSB bit-lane of each chain.
    const float kmask = ((lane & 7) == 7) ? 0.0f : 1.0f;

    const unsigned* bp0 = pk + og0 * (NG * 64) + lane;   // +64 per 32-step group
    const unsigned* bp1 = pk + og1 * (NG * 64) + lane;
    const int*      xp  = (const int*)(x + b * F_DIM) + lane; // +64 per superblock

    // Double-buffered superblock state, all names static (no runtime indexing).
    // Slot A = superblock sb, slot B = superblock sb+1.
    unsigned pA00 = bp0[0 * 64], pA01 = bp0[1 * 64];   // chain0 steps 0-31,32-63
    unsigned pA10 = bp1[0 * 64], pA11 = bp1[1 * 64];   // chain1
    int      xA   = xp[0 * 64];
    unsigned pB00 = bp0[2 * 64], pB01 = bp0[3 * 64];
    unsigned pB10 = bp1[2 * 64], pB11 = bp1[3 * 64];
    int      xB   = xp[1 * 64];

    float s0 = 0.0f, h0 = 0.0f;   // chain0 state; c_i = dpp(h_{i-1}), h init 0
    float s1 = 0.0f, h1 = 0.0f;   // chain1 state

    // 64 exact steps for BOTH chains from 4 pk dwords + 1 lane-sliced x dword.
#define STEP2x64(PKa0, PKa1, PKb0, PKb1, XV)                               \
    _Pragma("unroll")                                                      \
    for (int u = 0; u < 64; ++u) {                                         \
        int      xs    = __builtin_amdgcn_readlane((XV), u); /* shared */  \
        unsigned bits0 = (u < 32) ? (PKa0) : (PKa1);                       \
        unsigned bits1 = (u < 32) ? (PKb0) : (PKb1);                       \
        int      m0    = sext_bit(bits0, u & 31);                          \
        int      m1    = sext_bit(bits1, u & 31);                          \
        float    a0    = __int_as_float(m0 & xs);  /* == x*hard, x >= 0 */ \
        float    a1    = __int_as_float(m1 & xs);                          \
        float    cn0   = dpp_row_shr1(h0);         /* inputs are old */    \
        float    cn1   = dpp_row_shr1(h1);                                 \
        float    uu0   = s0 + a0;                                          \
        float    uu1   = s1 + a1;                                          \
        float    t0    = uu0 + cn0;                                        \
        float    t1    = uu1 + cn1;                                        \
        bool     ge0   = (t0 >= 2.0f);                                     \
        bool     ge1   = (t1 >= 2.0f);                                     \
        h0 = ge0 ? kmask : 0.0f;                                           \
        h1 = ge1 ? kmask : 0.0f;                                           \
        s0 = ge0 ? (t0 - 2.0f) : t0;   /* exact on [2,4) */                \
        s1 = ge1 ? (t1 - 2.0f) : t1;                                       \
    }

    for (int sb = 0; sb < NSB; sb += 2) {   // 16 iterations, 2 superblocks each
        STEP2x64(pA00, pA01, pA10, pA11, xA);
        {   // refill slot A for superblock sb+2 (clamped tail re-read, harmless)
            int nsb = sb + 2; int csb = (nsb < NSB) ? nsb : (NSB - 2);
            pA00 = bp0[(2 * csb + 0) * 64];
            pA01 = bp0[(2 * csb + 1) * 64];
            pA10 = bp1[(2 * csb + 0) * 64];
            pA11 = bp1[(2 * csb + 1) * 64];
            xA   = xp[csb * 64];
        }
        STEP2x64(pB00, pB01, pB10, pB11, xB);
        {   // refill slot B for superblock sb+3
            int nsb = sb + 3; int csb = (nsb < NSB) ? nsb : (NSB - 2);
            pB00 = bp0[(2 * csb + 0) * 64];
            pB01 = bp0[(2 * csb + 1) * 64];
            pB10 = bp1[(2 * csb + 0) * 64];
            pB11 = bp1[(2 * csb + 1) * 64];
            xB   = xp[csb * 64];
        }
    }
#undef STEP2x64

    float cf0 = dpp_row_shr1(h0);   // reference returns the post-shift carry
    float cf1 = dpp_row_shr1(h1);
    out[b * K_DIM + k0]                 = s0;
    out[b * K_DIM + k1]                 = s1;
    out[B_DIM * K_DIM + b * K_DIM + k0] = cf0;
    out[B_DIM * K_DIM + b * K_DIM + k1] = cf1;
}

// ---------------- fallback (direct-w kernel) if ws is too small ------------
#define U_FB  16
#define NB_FB 4
__global__ __launch_bounds__(64, 1) void csa_fallback(const float* __restrict__ x,
                                                      const float* __restrict__ weight,
                                                      float* __restrict__ out) {
    const int lane = threadIdx.x;
    const int og   = blockIdx.x + 8 * blockIdx.y;
    const int b    = blockIdx.z;
    const int k    = og * 64 + lane;
    const float kmask = ((lane & 7) == 7) ? 0.0f : 1.0f;
    int zero;
    asm volatile("v_mov_b32 %0, 0" : "=v"(zero));
    const float*  wp  = weight + k;
    const float4* xp4 = (const float4*)(x + b * F_DIM) + zero;
    float  wb[NB_FB][U_FB];
    float4 xb[NB_FB][U_FB / 4];
#pragma unroll
    for (int p = 0; p < NB_FB; ++p) {
#pragma unroll
        for (int u = 0; u < U_FB; ++u) wb[p][u] = wp[(p * U_FB + u) * K_DIM];
#pragma unroll
        for (int q = 0; q < U_FB / 4; ++q) xb[p][q] = xp4[(p * U_FB) / 4 + q];
    }
    float s = 0.0f, c = 0.0f;
    for (int f0 = 0; f0 < F_DIM; f0 += NB_FB * U_FB) {
#pragma unroll
        for (int p = 0; p < NB_FB; ++p) {
            const float* xf = (const float*)&xb[p][0];
#pragma unroll
            for (int u = 0; u < U_FB; ++u) {
                float a  = (wb[p][u] >= 0.5f) ? xf[u] : 0.0f;
                float uu = s + a;
                float t  = uu + c;
                bool  ge = (t >= 2.0f);
                float hh = ge ? kmask : 0.0f;
                s = ge ? (t - 2.0f) : t;
                c = dpp_row_shr1(hh);
            }
            int fb = f0 + p * U_FB + NB_FB * U_FB;
            int fc = (fb <= F_DIM - U_FB) ? fb : (F_DIM - U_FB);
#pragma unroll
            for (int u = 0; u < U_FB; ++u) wb[p][u] = wp[(fc + u) * K_DIM];
#pragma unroll
            for (int q = 0; q < U_FB / 4; ++q) xb[p][q] = xp4[fc / 4 + q];
        }
    }
    out[b * K_DIM + k]                 = s;
    out[B_DIM * K_DIM + b * K_DIM + k] = c;
}

extern "C" void kernel_launch(void* const* d_in, const int* in_sizes, int n_in,
                              void* d_out, int out_size, void* d_ws, size_t ws_size,
                              hipStream_t stream) {
    (void)in_sizes; (void)n_in; (void)out_size;
    const float* x      = (const float*)d_in[0];
    const float* weight = (const float*)d_in[1];
    float* out          = (float*)d_out;

    if (ws_size >= (size_t)PK_BYTES && d_ws != nullptr) {
        unsigned* pk = (unsigned*)d_ws;
        pack_kernel<<<dim3(64, 64, 1), dim3(64), 0, stream>>>(weight, pk);
        csa_main<<<dim3(8, 4, 8), dim3(64), 0, stream>>>(x, pk, out);
    } else {
        csa_fallback<<<dim3(8, 8, 8), dim3(64), 0, stream>>>(x, weight, out);
    }
}

// Round 4
// 121.867 us; speedup vs baseline: 1.2091x; 1.2091x over previous
//
#include <hip/hip_runtime.h>

// binary_decoder: bit-exact float32 emulation of the reference's sequential
// carry-save adder.
//
// Round-8 = round-7 with ONE fix. Round 7 failed (absmax 1.86) because the
// prologue asm declared [h]"=v" (not earlyclobber) while writing h BEFORE
// reading input a0 -> the allocator may alias a0 to h, and v_mov_b32 h,0
// clobbers a0 before v_add_f32 uu,0,a0 reads it => uu_0 lost feature 0's
// addend in every chain (error < 2, matches 1.86). Fix: [h]"=&v".
// Main step blob audited clean: all mid-blob pure outputs are "=&v"; tied
// "+v" operands are live-in and cannot alias other inputs.
//
// HW model (r4/r5/r6 data): a single wave issues at most one instruction
// per ~4.5 cy; period == #VALU/step * ~4.5 regardless of ILP. So minimize
// per-wave VALU count. 1 chain/wave, 512 waves.
//
// Per-step stream is ONE 8-instruction asm blob:
//   v_add_f32_dpp t, h, uu      ; carry-shift fused into the add
//   v_mul_f32     g, 0.5, t
//   v_floor_f32   c, g          ; c = floor(t/2), exact (t in [0,4))
//   v_fma_f32     s, c, -2.0, t ; s' = t-2c, exact (Sterbenz on [2,4))
//   v_mul_f32     h, c, km      ; h' = c*kmask (MSB carry dropped)
//   v_add_f32     uu, s, a      ; uu_{f+1} = s' + a_{f+1} (a pipelined ahead)
//   v_bfe_i32     m, bits, J, 1 ; prep a_{f+2} (sign-extended bit)
//   v_and_b32     a, s_x, m     ; a_{f+2} = bit ? x : +0 (x >= 0), x in SGPR
// vcc-free, no VALU->SGPR writes. DPP hazard (>=2 wait states before a DPP
// reads a VALU-written VGPR) by construction: h @5, uu @6 of 8, dpp @1.
// x via uniform loads (scalar path, zero VALU); pk via per-lane loads.
//
// Exactness: floor form computes the reference's own half=floor(t*0.5),
// s=t-2*half bitwise (t<4; halving exact; fma(c,-2,t) exact; h=c*km in
// {0,1}). t = (s+a)+c association matches reference. Carry shift via DPP
// row_shr:1 with bound_ctrl reads-zero; MSB pre-masked by kmask.

#define F_DIM 2048
#define K_DIM 4096
#define B_DIM 8
#define NG    (F_DIM / 32)   // 64 packed dwords per chain-column
#define NSB   (F_DIM / 64)   // 32 superblocks of 64 steps

#define PK_BYTES (64 * NG * 64 * 4)  // 1 MB: [og][f32][lane] dwords

typedef int v16i __attribute__((ext_vector_type(16)));

__device__ __forceinline__ float dpp_row_shr1(float v) {
    int r = __builtin_amdgcn_update_dpp(0, __float_as_int(v), 0x111, 0xf, 0xf, true);
    return __int_as_float(r);
}

__device__ __forceinline__ int sext_bit(unsigned bits, int u) {
#if __has_builtin(__builtin_amdgcn_sbfe)
    return __builtin_amdgcn_sbfe((int)bits, (unsigned)u, 1u);
#else
    return ((int)(bits << (31 - u))) >> 31;
#endif
}

// ---------------- pass 1: pack (w >= 0.5) bits -----------------------------
__global__ __launch_bounds__(64) void pack_kernel(const float* __restrict__ w,
                                                  unsigned* __restrict__ pk) {
    const int lane = threadIdx.x;
    const int og   = blockIdx.x;
    const int f32  = blockIdx.y;
    const float* wp = w + og * 64 + lane;
    unsigned bits = 0;
#pragma unroll
    for (int j = 0; j < 32; ++j) {
        float wv = wp[(f32 * 32 + j) * K_DIM];
        bits |= (wv >= 0.5f ? 1u : 0u) << j;
    }
    pk[(og * 64 + f32) * 64 + lane] = bits;
}

// ---------------- pass 2: the sequential chain -----------------------------

#define B(PKv, JLIT, XVAL) {                                                  \
    const int xs_ = (XVAL);                                                   \
    asm("v_add_f32_dpp %[t], %[h], %[uu] row_shr:1 row_mask:0xf bank_mask:0xf bound_ctrl:0\n\t" \
        "v_mul_f32 %[g], 0.5, %[t]\n\t"                                       \
        "v_floor_f32 %[c], %[g]\n\t"                                          \
        "v_fma_f32 %[s], %[c], -2.0, %[t]\n\t"                                \
        "v_mul_f32 %[h], %[c], %[km]\n\t"                                     \
        "v_add_f32 %[uu], %[s], %[a]\n\t"                                     \
        "v_bfe_i32 %[m], %[bits], " #JLIT ", 1\n\t"                           \
        "v_and_b32 %[a], %[xs], %[m]"                                         \
        : [t]"=&v"(t_), [g]"=&v"(g_), [c]"=&v"(c_), [m]"=&v"(m_),             \
          [s]"+v"(s), [h]"+v"(h), [uu]"+v"(uu), [a]"+v"(a)                    \
        : [bits]"v"(PKv), [xs]"s"(xs_), [km]"v"(km));                         \
}

// 64 steps of superblock S. Blob j (step S*64+j) preps a for step S*64+j+2:
// bit e=j+2 of the window {PN[1:0], P1, P0}; x element e from four dwordx16
// chunks of this superblock + the next superblock's first chunk.
#define SB64(P0, P1, PN, CQ, CQN) {                                           \
    v16i q0 = xv[(CQ)+0], q1 = xv[(CQ)+1], q2 = xv[(CQ)+2], q3 = xv[(CQ)+3];  \
    v16i qn = xv[(CQN)];                                                      \
    B(P0, 2,q0[ 2]) B(P0, 3,q0[ 3]) B(P0, 4,q0[ 4]) B(P0, 5,q0[ 5])          \
    B(P0, 6,q0[ 6]) B(P0, 7,q0[ 7]) B(P0, 8,q0[ 8]) B(P0, 9,q0[ 9])          \
    B(P0,10,q0[10]) B(P0,11,q0[11]) B(P0,12,q0[12]) B(P0,13,q0[13])          \
    B(P0,14,q0[14]) B(P0,15,q0[15])                                           \
    B(P0,16,q1[ 0]) B(P0,17,q1[ 1]) B(P0,18,q1[ 2]) B(P0,19,q1[ 3])          \
    B(P0,20,q1[ 4]) B(P0,21,q1[ 5]) B(P0,22,q1[ 6]) B(P0,23,q1[ 7])          \
    B(P0,24,q1[ 8]) B(P0,25,q1[ 9]) B(P0,26,q1[10]) B(P0,27,q1[11])          \
    B(P0,28,q1[12]) B(P0,29,q1[13]) B(P0,30,q1[14]) B(P0,31,q1[15])          \
    B(P1, 0,q2[ 0]) B(P1, 1,q2[ 1]) B(P1, 2,q2[ 2]) B(P1, 3,q2[ 3])          \
    B(P1, 4,q2[ 4]) B(P1, 5,q2[ 5]) B(P1, 6,q2[ 6]) B(P1, 7,q2[ 7])          \
    B(P1, 8,q2[ 8]) B(P1, 9,q2[ 9]) B(P1,10,q2[10]) B(P1,11,q2[11])          \
    B(P1,12,q2[12]) B(P1,13,q2[13]) B(P1,14,q2[14]) B(P1,15,q2[15])          \
    B(P1,16,q3[ 0]) B(P1,17,q3[ 1]) B(P1,18,q3[ 2]) B(P1,19,q3[ 3])          \
    B(P1,20,q3[ 4]) B(P1,21,q3[ 5]) B(P1,22,q3[ 6]) B(P1,23,q3[ 7])          \
    B(P1,24,q3[ 8]) B(P1,25,q3[ 9]) B(P1,26,q3[10]) B(P1,27,q3[11])          \
    B(P1,28,q3[12]) B(P1,29,q3[13]) B(P1,30,q3[14]) B(P1,31,q3[15])          \
    B(PN, 0,qn[ 0]) B(PN, 1,qn[ 1])                                           \
}

__global__ __launch_bounds__(64, 1) void csa_main(const float* __restrict__ x,
                                                  const unsigned* __restrict__ pk,
                                                  float* __restrict__ out) {
    const int lane = threadIdx.x;
    const int og   = blockIdx.x + 8 * blockIdx.y;  // 0..63
    const int b    = blockIdx.z;                   // 0..7
    const int k    = og * 64 + lane;

    const float kmf = ((lane & 7) == 7) ? 0.0f : 1.0f;
    float km = kmf;

    const unsigned* bp = pk + og * (NG * 64) + lane;      // dword g at bp[g*64]
    const v16i*     xv = (const v16i*)(x + b * F_DIM);    // uniform -> scalar path
    const int*      xi = (const int*)(x + b * F_DIM);

    // pk double-buffer: slot A = superblock sb, slot B = sb+1.
    unsigned pA0 = bp[0 * 64], pA1 = bp[1 * 64];
    unsigned pB0 = bp[2 * 64], pB1 = bp[3 * 64];

    // Prologue: uu_0 = 0 + a_0; a register enters holding a_1; h = 0.
    int   xs0 = xi[0], xs1 = xi[1];
    float a0  = __int_as_float(sext_bit(pA0, 0) & xs0);
    float a   = __int_as_float(sext_bit(pA0, 1) & xs1);
    float s = 0.0f, h, uu;
    float t_, g_, c_;
    int   m_;
    asm("v_mov_b32 %[h], 0\n\t"
        "v_add_f32 %[uu], 0, %[a0]\n\t"
        "s_nop 1"
        : [h]"=&v"(h), [uu]"=&v"(uu)    // BOTH earlyclobber: h written before a0 is read
        : [a0]"v"(a0));

#pragma clang loop unroll(disable)
    for (int sb = 0; sb < NSB; sb += 2) {   // 16 iterations, 128 steps each
        SB64(pA0, pA1, pB0, sb * 4, sb * 4 + 4);
        {   // refill slot A -> superblock sb+2 (clamped tail re-read)
            int nsb = sb + 2; int csb = (nsb < NSB) ? nsb : (NSB - 2);
            pA0 = bp[(2 * csb + 0) * 64];
            pA1 = bp[(2 * csb + 1) * 64];
        }
        int cqn = (sb * 4 + 8 < 128) ? (sb * 4 + 8) : 127;  // dummy x at tail
        SB64(pB0, pB1, pA0, sb * 4 + 4, cqn);
        {   // refill slot B -> superblock sb+3
            int nsb = sb + 3; int csb = (nsb < NSB) ? nsb : (NSB - 2);
            pB0 = bp[(2 * csb + 0) * 64];
            pB1 = bp[(2 * csb + 1) * 64];
        }
    }

    float cfin = dpp_row_shr1(h);   // post-shift final carry
    out[b * K_DIM + k]                 = s;
    out[B_DIM * K_DIM + b * K_DIM + k] = cfin;
}

#undef SB64
#undef B

// ---------------- fallback (direct-w kernel) if ws is too small ------------
#define U_FB  16
#define NB_FB 4
__global__ __launch_bounds__(64, 1) void csa_fallback(const float* __restrict__ x,
                                                      const float* __restrict__ weight,
                                                      float* __restrict__ out) {
    const int lane = threadIdx.x;
    const int og   = blockIdx.x + 8 * blockIdx.y;
    const int b    = blockIdx.z;
    const int k    = og * 64 + lane;
    const float kmask = ((lane & 7) == 7) ? 0.0f : 1.0f;
    int zero;
    asm volatile("v_mov_b32 %0, 0" : "=v"(zero));
    const float*  wp  = weight + k;
    const float4* xp4 = (const float4*)(x + b * F_DIM) + zero;
    float  wb[NB_FB][U_FB];
    float4 xb[NB_FB][U_FB / 4];
#pragma unroll
    for (int p = 0; p < NB_FB; ++p) {
#pragma unroll
        for (int u = 0; u < U_FB; ++u) wb[p][u] = wp[(p * U_FB + u) * K_DIM];
#pragma unroll
        for (int q = 0; q < U_FB / 4; ++q) xb[p][q] = xp4[(p * U_FB) / 4 + q];
    }
    float s = 0.0f, c = 0.0f;
    for (int f0 = 0; f0 < F_DIM; f0 += NB_FB * U_FB) {
#pragma unroll
        for (int p = 0; p < NB_FB; ++p) {
            const float* xf = (const float*)&xb[p][0];
#pragma unroll
            for (int u = 0; u < U_FB; ++u) {
                float av = (wb[p][u] >= 0.5f) ? xf[u] : 0.0f;
                float uu = s + av;
                float t  = uu + c;
                bool  ge = (t >= 2.0f);
                float hh = ge ? kmask : 0.0f;
                s = ge ? (t - 2.0f) : t;
                c = dpp_row_shr1(hh);
            }
            int fb = f0 + p * U_FB + NB_FB * U_FB;
            int fc = (fb <= F_DIM - U_FB) ? fb : (F_DIM - U_FB);
#pragma unroll
            for (int u = 0; u < U_FB; ++u) wb[p][u] = wp[(fc + u) * K_DIM];
#pragma unroll
            for (int q = 0; q < U_FB / 4; ++q) xb[p][q] = xp4[fc / 4 + q];
        }
    }
    out[b * K_DIM + k]                 = s;
    out[B_DIM * K_DIM + b * K_DIM + k] = c;
}

extern "C" void kernel_launch(void* const* d_in, const int* in_sizes, int n_in,
                              void* d_out, int out_size, void* d_ws, size_t ws_size,
                              hipStream_t stream) {
    (void)in_sizes; (void)n_in; (void)out_size;
    const float* x      = (const float*)d_in[0];
    const float* weight = (const float*)d_in[1];
    float* out          = (float*)d_out;

    if (ws_size >= (size_t)PK_BYTES && d_ws != nullptr) {
        unsigned* pk = (unsigned*)d_ws;
        pack_kernel<<<dim3(64, 64, 1), dim3(64), 0, stream>>>(weight, pk);
        csa_main<<<dim3(8, 8, 8), dim3(64), 0, stream>>>(x, pk, out);
    } else {
        csa_fallback<<<dim3(8, 8, 8), dim3(64), 0, stream>>>(x, weight, out);
    }
}

// Round 5
// 114.182 us; speedup vs baseline: 1.2905x; 1.0673x over previous
//
#include <hip/hip_runtime.h>

// binary_decoder: bit-exact float32 emulation of the reference's sequential
// carry-save adder.
//
// Round-9. HW model refined from r4/r5/r6/r8: period/step =
// max(#instr * ~4.6 cy issue, chain_links * ~9-10 cy single-wave dependent
// latency). r8 (8 instr, 5-6 link cycle with DPP on the critical path) was
// latency-bound at 57 cy. This round: 6 instr, 4-link cycle, DPP moved to
// the slack path.
//
// Bit-trick carry: for t in [0,4), (t>=2) <=> bit30 of IEEE bits, so
//   c2 = as_float(bits(t) & 0x40000000) in {0, 2.0}   -- ONE v_and_b32,
// with 0x40000000 encoded as the free inline constant 2.0. c2 doubles as
// the carry state (no separate h): the x0.5 and the group-LSB mask fold
// into one per-lane constant kq = (lane&7==0) ? 0 : 0.5 applied at the
// DESTINATION via v_fmac_f32_dpp:  t' = uu' + dpp_row_shr1(c2) * kq.
// Product in {0,1} exact => fmac rounds bitwise-identically to uu + c.
//
// Per-step blob (6 instr):
//   v_fmac_f32_dpp uu, c2, kq row_shr:1  ; t = uu + carry_in   (cycle link 4)
//   v_and_b32      c2, 2.0, uu           ; carry out in {0,2}  (link 1)
//   v_sub_f32      s,  uu, c2            ; s' = t - 2*half, exact (link 2)
//   v_add_f32      uu, s,  a             ; uu' = s' + a_next   (link 3)
//   v_bfe_i32      m,  bits, J, 1        ; off-chain a-prep (+2 ahead)
//   v_and_b32      a,  s_x, m            ; a = bit ? x : +0  (x>=0, SGPR x)
// DPP hazard (>=2 instrs between VGPR write and DPP read): c2 written at
// slot 2, next blob's fmac reads it via DPP 4 instrs later. Prologue covers
// the first blob with s_nop 1. Mask equivalence: receiver-side kq=0 at
// lane&7==0  <=>  old source-side km=0 at lane&7==7; row-crossing lanes
// (16k) get 0 from bound_ctrl AND kq=0. Final carry = dpp(c2)*kq in {0,1}.
//
// Exactness: t<4 always (s<2, a<1, c<=1); bit30 test exact; Sterbenz on
// [2,4); +0 identities hold (all quantities >= +0). Association
// t = (s+a)+c matches the reference. absmax 0.0 expected.

#define F_DIM 2048
#define K_DIM 4096
#define B_DIM 8
#define NG    (F_DIM / 32)   // 64 packed dwords per chain-column
#define NSB   (F_DIM / 64)   // 32 superblocks of 64 steps

#define PK_BYTES (64 * NG * 64 * 4)  // 1 MB: [og][f32][lane] dwords

typedef int v16i __attribute__((ext_vector_type(16)));

__device__ __forceinline__ float dpp_row_shr1(float v) {
    int r = __builtin_amdgcn_update_dpp(0, __float_as_int(v), 0x111, 0xf, 0xf, true);
    return __int_as_float(r);
}

__device__ __forceinline__ int sext_bit(unsigned bits, int u) {
#if __has_builtin(__builtin_amdgcn_sbfe)
    return __builtin_amdgcn_sbfe((int)bits, (unsigned)u, 1u);
#else
    return ((int)(bits << (31 - u))) >> 31;
#endif
}

// ---------------- pass 1: pack (w >= 0.5) bits -----------------------------
__global__ __launch_bounds__(64) void pack_kernel(const float* __restrict__ w,
                                                  unsigned* __restrict__ pk) {
    const int lane = threadIdx.x;
    const int og   = blockIdx.x;
    const int f32  = blockIdx.y;
    const float* wp = w + og * 64 + lane;
    unsigned bits = 0;
#pragma unroll
    for (int j = 0; j < 32; ++j) {
        float wv = wp[(f32 * 32 + j) * K_DIM];
        bits |= (wv >= 0.5f ? 1u : 0u) << j;
    }
    pk[(og * 64 + f32) * 64 + lane] = bits;
}

// ---------------- pass 2: the sequential chain -----------------------------

#define B(PKv, JLIT, XVAL) {                                                  \
    const int xs_ = (XVAL);                                                   \
    asm("v_fmac_f32_dpp %[uu], %[c2], %[kq] row_shr:1 row_mask:0xf bank_mask:0xf bound_ctrl:0\n\t" \
        "v_and_b32 %[c2], 2.0, %[uu]\n\t"                                     \
        "v_sub_f32 %[s], %[uu], %[c2]\n\t"                                    \
        "v_add_f32 %[uu], %[s], %[a]\n\t"                                     \
        "v_bfe_i32 %[m], %[bits], " #JLIT ", 1\n\t"                           \
        "v_and_b32 %[a], %[xs], %[m]"                                         \
        : [m]"=&v"(m_),                                                       \
          [s]"+v"(s), [uu]"+v"(uu), [a]"+v"(a), [c2]"+v"(c2)                  \
        : [bits]"v"(PKv), [xs]"s"(xs_), [kq]"v"(kq));                         \
}

// 64 steps of superblock S. Blob j (step S*64+j) preps a for step S*64+j+2:
// bit e=j+2 of the window {PN[1:0], P1, P0}; x element e from four dwordx16
// chunks of this superblock + the next superblock's first chunk.
#define SB64(P0, P1, PN, CQ, CQN) {                                           \
    v16i q0 = xv[(CQ)+0], q1 = xv[(CQ)+1], q2 = xv[(CQ)+2], q3 = xv[(CQ)+3];  \
    v16i qn = xv[(CQN)];                                                      \
    B(P0, 2,q0[ 2]) B(P0, 3,q0[ 3]) B(P0, 4,q0[ 4]) B(P0, 5,q0[ 5])          \
    B(P0, 6,q0[ 6]) B(P0, 7,q0[ 7]) B(P0, 8,q0[ 8]) B(P0, 9,q0[ 9])          \
    B(P0,10,q0[10]) B(P0,11,q0[11]) B(P0,12,q0[12]) B(P0,13,q0[13])          \
    B(P0,14,q0[14]) B(P0,15,q0[15])                                           \
    B(P0,16,q1[ 0]) B(P0,17,q1[ 1]) B(P0,18,q1[ 2]) B(P0,19,q1[ 3])          \
    B(P0,20,q1[ 4]) B(P0,21,q1[ 5]) B(P0,22,q1[ 6]) B(P0,23,q1[ 7])          \
    B(P0,24,q1[ 8]) B(P0,25,q1[ 9]) B(P0,26,q1[10]) B(P0,27,q1[11])          \
    B(P0,28,q1[12]) B(P0,29,q1[13]) B(P0,30,q1[14]) B(P0,31,q1[15])          \
    B(P1, 0,q2[ 0]) B(P1, 1,q2[ 1]) B(P1, 2,q2[ 2]) B(P1, 3,q2[ 3])          \
    B(P1, 4,q2[ 4]) B(P1, 5,q2[ 5]) B(P1, 6,q2[ 6]) B(P1, 7,q2[ 7])          \
    B(P1, 8,q2[ 8]) B(P1, 9,q2[ 9]) B(P1,10,q2[10]) B(P1,11,q2[11])          \
    B(P1,12,q2[12]) B(P1,13,q2[13]) B(P1,14,q2[14]) B(P1,15,q2[15])          \
    B(P1,16,q3[ 0]) B(P1,17,q3[ 1]) B(P1,18,q3[ 2]) B(P1,19,q3[ 3])          \
    B(P1,20,q3[ 4]) B(P1,21,q3[ 5]) B(P1,22,q3[ 6]) B(P1,23,q3[ 7])          \
    B(P1,24,q3[ 8]) B(P1,25,q3[ 9]) B(P1,26,q3[10]) B(P1,27,q3[11])          \
    B(P1,28,q3[12]) B(P1,29,q3[13]) B(P1,30,q3[14]) B(P1,31,q3[15])          \
    B(PN, 0,qn[ 0]) B(PN, 1,qn[ 1])                                           \
}

__global__ __launch_bounds__(64, 1) void csa_main(const float* __restrict__ x,
                                                  const unsigned* __restrict__ pk,
                                                  float* __restrict__ out) {
    const int lane = threadIdx.x;
    const int og   = blockIdx.x + 8 * blockIdx.y;  // 0..63
    const int b    = blockIdx.z;                   // 0..7
    const int k    = og * 64 + lane;

    // Destination-side carry mask: zero at each group's LSB lane, else 0.5.
    const float kqf = ((lane & 7) == 0) ? 0.0f : 0.5f;
    float kq = kqf;

    const unsigned* bp = pk + og * (NG * 64) + lane;      // dword g at bp[g*64]
    const v16i*     xv = (const v16i*)(x + b * F_DIM);    // uniform -> scalar path
    const int*      xi = (const int*)(x + b * F_DIM);

    // pk double-buffer: slot A = superblock sb, slot B = sb+1.
    unsigned pA0 = bp[0 * 64], pA1 = bp[1 * 64];
    unsigned pB0 = bp[2 * 64], pB1 = bp[3 * 64];

    // Prologue: uu = 0 + a_0 (== a_0 bitwise, both >= +0); a holds a_1;
    // c2 = 0. s_nop 1 covers the first blob's DPP-read-of-c2 hazard.
    int   xs0 = xi[0], xs1 = xi[1];
    float a0  = __int_as_float(sext_bit(pA0, 0) & xs0);
    float a   = __int_as_float(sext_bit(pA0, 1) & xs1);
    float s = 0.0f, uu, c2;
    int   m_;
    asm("v_mov_b32 %[c2], 0\n\t"
        "v_mov_b32 %[uu], %[a0]\n\t"
        "s_nop 1"
        : [c2]"=&v"(c2), [uu]"=&v"(uu)   // earlyclobber: writes precede a0 read (r7 lesson)
        : [a0]"v"(a0));

#pragma clang loop unroll(disable)
    for (int sb = 0; sb < NSB; sb += 2) {   // 16 iterations, 128 steps each
        SB64(pA0, pA1, pB0, sb * 4, sb * 4 + 4);
        {   // refill slot A -> superblock sb+2 (clamped tail re-read)
            int nsb = sb + 2; int csb = (nsb < NSB) ? nsb : (NSB - 2);
            pA0 = bp[(2 * csb + 0) * 64];
            pA1 = bp[(2 * csb + 1) * 64];
        }
        int cqn = (sb * 4 + 8 < 128) ? (sb * 4 + 8) : 127;  // dummy x at tail
        SB64(pB0, pB1, pA0, sb * 4 + 4, cqn);
        {   // refill slot B -> superblock sb+3
            int nsb = sb + 3; int csb = (nsb < NSB) ? nsb : (NSB - 2);
            pB0 = bp[(2 * csb + 0) * 64];
            pB1 = bp[(2 * csb + 1) * 64];
        }
    }

    // Final carry: shift last c2 (in {0,2}) and scale/mask by kq -> {0,1}.
    float cfin = dpp_row_shr1(c2) * kq;
    out[b * K_DIM + k]                 = s;
    out[B_DIM * K_DIM + b * K_DIM + k] = cfin;
}

#undef SB64
#undef B

// ---------------- fallback (direct-w kernel) if ws is too small ------------
#define U_FB  16
#define NB_FB 4
__global__ __launch_bounds__(64, 1) void csa_fallback(const float* __restrict__ x,
                                                      const float* __restrict__ weight,
                                                      float* __restrict__ out) {
    const int lane = threadIdx.x;
    const int og   = blockIdx.x + 8 * blockIdx.y;
    const int b    = blockIdx.z;
    const int k    = og * 64 + lane;
    const float kmask = ((lane & 7) == 7) ? 0.0f : 1.0f;
    int zero;
    asm volatile("v_mov_b32 %0, 0" : "=v"(zero));
    const float*  wp  = weight + k;
    const float4* xp4 = (const float4*)(x + b * F_DIM) + zero;
    float  wb[NB_FB][U_FB];
    float4 xb[NB_FB][U_FB / 4];
#pragma unroll
    for (int p = 0; p < NB_FB; ++p) {
#pragma unroll
        for (int u = 0; u < U_FB; ++u) wb[p][u] = wp[(p * U_FB + u) * K_DIM];
#pragma unroll
        for (int q = 0; q < U_FB / 4; ++q) xb[p][q] = xp4[(p * U_FB) / 4 + q];
    }
    float s = 0.0f, c = 0.0f;
    for (int f0 = 0; f0 < F_DIM; f0 += NB_FB * U_FB) {
#pragma unroll
        for (int p = 0; p < NB_FB; ++p) {
            const float* xf = (const float*)&xb[p][0];
#pragma unroll
            for (int u = 0; u < U_FB; ++u) {
                float av = (wb[p][u] >= 0.5f) ? xf[u] : 0.0f;
                float uu = s + av;
                float t  = uu + c;
                bool  ge = (t >= 2.0f);
                float hh = ge ? kmask : 0.0f;
                s = ge ? (t - 2.0f) : t;
                c = dpp_row_shr1(hh);
            }
            int fb = f0 + p * U_FB + NB_FB * U_FB;
            int fc = (fb <= F_DIM - U_FB) ? fb : (F_DIM - U_FB);
#pragma unroll
            for (int u = 0; u < U_FB; ++u) wb[p][u] = wp[(fc + u) * K_DIM];
#pragma unroll
            for (int q = 0; q < U_FB / 4; ++q) xb[p][q] = xp4[fc / 4 + q];
        }
    }
    out[b * K_DIM + k]                 = s;
    out[B_DIM * K_DIM + b * K_DIM + k] = c;
}

extern "C" void kernel_launch(void* const* d_in, const int* in_sizes, int n_in,
                              void* d_out, int out_size, void* d_ws, size_t ws_size,
                              hipStream_t stream) {
    (void)in_sizes; (void)n_in; (void)out_size;
    const float* x      = (const float*)d_in[0];
    const float* weight = (const float*)d_in[1];
    float* out          = (float*)d_out;

    if (ws_size >= (size_t)PK_BYTES && d_ws != nullptr) {
        unsigned* pk = (unsigned*)d_ws;
        pack_kernel<<<dim3(64, 64, 1), dim3(64), 0, stream>>>(weight, pk);
        csa_main<<<dim3(8, 8, 8), dim3(64), 0, stream>>>(x, pk, out);
    } else {
        csa_fallback<<<dim3(8, 8, 8), dim3(64), 0, stream>>>(x, weight, out);
    }
}